// Round 8
// baseline (338.979 us; speedup 1.0000x reference)
//
#include <hip/hip_runtime.h>
#include <stdint.h>

#define SEQ 2048
#define EMB 1024
#define NROWS 4096  // 2 batches * 2048

typedef __bf16 bf16x8 __attribute__((ext_vector_type(8)));
typedef float f32x4 __attribute__((ext_vector_type(4)));
typedef unsigned short ushort8 __attribute__((ext_vector_type(8)));

__device__ __forceinline__ unsigned short f2bf(float f) {
  unsigned int u = __float_as_uint(f);
  u += 0x7fffu + ((u >> 16) & 1u);
  return (unsigned short)(u >> 16);
}

__device__ __forceinline__ f32x4 mfma16(bf16x8 a, bf16x8 b, f32x4 c) {
  return __builtin_amdgcn_mfma_f32_16x16x32_bf16(a, b, c, 0, 0, 0);
}

// async global->LDS, 16B per lane; lds dest = wave-uniform base + lane*16
__device__ __forceinline__ void async_load16(const void* g, void* l) {
  auto gp = reinterpret_cast<__attribute__((address_space(1))) void*>(
      reinterpret_cast<uintptr_t>(g));
  auto lp = reinterpret_cast<__attribute__((address_space(3))) void*>(
      reinterpret_cast<uintptr_t>(l));
  __builtin_amdgcn_global_load_lds(gp, lp, 16, 0, 0);
}

// ---------------- fp32 -> bf16 convert, both inputs in one launch ----------------
__global__ __launch_bounds__(256) void cvt2(const float* __restrict__ t,
                                            const float* __restrict__ s,
                                            unsigned short* __restrict__ tb,
                                            unsigned short* __restrict__ sb) {
  int i = blockIdx.x * 256 + threadIdx.x;
  const float* x; unsigned short* y;
  if (i < NROWS * EMB / 4) { x = (const float*)t; y = tb; }
  else { x = (const float*)s; y = sb; i -= NROWS * EMB / 4; }
  float4 v = ((const float4*)x)[i];
  ushort4 o;
  o.x = f2bf(v.x); o.y = f2bf(v.y); o.z = f2bf(v.z); o.w = f2bf(v.w);
  ((ushort4*)y)[i] = o;
}

// ---------------- 8x W[k][n] fp32 -> Wt[z*1024 + n][k] bf16 ----------------
__global__ __launch_bounds__(256) void wtrans8(const float* __restrict__ W0,
                                               const float* __restrict__ W1,
                                               const float* __restrict__ W2,
                                               const float* __restrict__ W3,
                                               const float* __restrict__ W4,
                                               const float* __restrict__ W5,
                                               const float* __restrict__ W6,
                                               const float* __restrict__ W7,
                                               unsigned short* __restrict__ Wt) {
  const float* Ws[8] = {W0, W1, W2, W3, W4, W5, W6, W7};
  const float* W = Ws[blockIdx.z];
  unsigned short* dst = Wt + ((size_t)blockIdx.z << 20);
  __shared__ unsigned short t[64][65];
  const int n0 = blockIdx.x * 64, k0 = blockIdx.y * 64;
#pragma unroll
  for (int i = 0; i < 16; ++i) {
    const int e = i * 256 + threadIdx.x;
    const int kk = e >> 6, nn = e & 63;
    t[kk][nn] = f2bf(W[(size_t)(k0 + kk) * EMB + n0 + nn]);
  }
  __syncthreads();
#pragma unroll
  for (int i = 0; i < 16; ++i) {
    const int e = i * 256 + threadIdx.x;
    const int nn = e >> 6, kk = e & 63;
    dst[(size_t)(n0 + nn) * EMB + k0 + kk] = t[kk][nn];
  }
}

// ------- 128x128 GEMM core, BK=64, XOR-swizzled LDS (conflict-free), 32 MFMA/iter -------
// Swizzle folded into GLOBAL source address (LDS dest stays linear for global_load_lds).
// SWAP=0: acc[i][j] = A-rows(i) x Bt-rows(j)  (C cols = Bt dim)
// SWAP=1: acc[i][j] = Bt-rows(i) x A-rows(j)  (C cols = A-row dim; lane's 4 regs are
//         4 CONSECUTIVE Bt-dim indices -> vectorizable epilogue stores)
template <int SWAP>
__device__ __forceinline__ void gemm_core64(const unsigned short* __restrict__ A,
                                            const unsigned short* __restrict__ Bt,
                                            int m0, int bt0,
                                            unsigned short* As, unsigned short* Bs,
                                            f32x4 (&acc)[4][4]) {
  const int tid = threadIdx.x;
  const int w = tid >> 6, lane = tid & 63;
  const int quad = lane >> 4, l16 = lane & 15;
  const int wm = w & 1, wn = w >> 1;
  const int sw8 = l16 & 7;

  // staging: wave w owns rows [w*32, w*32+32) of both As and Bs; 4 instrs each
  const int srow = lane >> 3, p8 = lane & 7;
  const unsigned short* Ag[4];
  const unsigned short* Bg[4];
#pragma unroll
  for (int i = 0; i < 4; ++i) {
    const int r = w * 32 + i * 8 + srow;
    Ag[i] = A + (size_t)(m0 + r) * EMB + ((p8 ^ (r & 7)) * 8);
    Bg[i] = Bt + (size_t)(bt0 + r) * EMB + ((p8 ^ (r & 7)) * 8);
  }
  unsigned short* AsB[4];
  unsigned short* BsB[4];
#pragma unroll
  for (int i = 0; i < 4; ++i) {
    AsB[i] = As + (w * 32 + i * 8) * 64;
    BsB[i] = Bs + (w * 32 + i * 8) * 64;
  }

  for (int kk = 0; kk < EMB; kk += 64) {
    __syncthreads();
#pragma unroll
    for (int i = 0; i < 4; ++i) {
      async_load16(Ag[i] + kk, AsB[i]);
      async_load16(Bg[i] + kk, BsB[i]);
    }
    __syncthreads();
#pragma unroll
    for (int h = 0; h < 2; ++h) {
      bf16x8 af[4], bfr[4];
#pragma unroll
      for (int im = 0; im < 4; ++im)
        af[im] = *(const bf16x8*)(As + (wm * 64 + im * 16 + l16) * 64 +
                                  (((h * 4 + quad) ^ sw8) * 8));
#pragma unroll
      for (int in = 0; in < 4; ++in)
        bfr[in] = *(const bf16x8*)(Bs + (wn * 64 + in * 16 + l16) * 64 +
                                   (((h * 4 + quad) ^ sw8) * 8));
#pragma unroll
      for (int i = 0; i < 4; ++i)
#pragma unroll
        for (int j = 0; j < 4; ++j)
          acc[i][j] = SWAP ? mfma16(bfr[i], af[j], acc[i][j])
                           : mfma16(af[i], bfr[j], acc[i][j]);
    }
  }
}

// ---------------- fused Q|K|V projection GEMM, BOTH directions ----------------
// grid (48, 32): idx = bx>>3 in 0..5 = dir*3 + {Q,K,V}; n0 = (bx&7)*128; m0 = by*128.
// dir0 = s2t (q from temp, kv from spat), dir1 = t2s.
// Q pre-scaled by 0.125*log2(e). V written TRANSPOSED into Vt[bh][d][key].
// Q/K use SWAP=1 (lane holds 4 consecutive output cols -> ushort4 stores).
__global__ __launch_bounds__(256, 3) void gemm_qkv(const unsigned short* __restrict__ tempb,
                                                   const unsigned short* __restrict__ spatb,
                                                   const unsigned short* __restrict__ Wt,
                                                   const float* __restrict__ bq0,
                                                   const float* __restrict__ bk0,
                                                   const float* __restrict__ bv0,
                                                   const float* __restrict__ bq1,
                                                   const float* __restrict__ bk1,
                                                   const float* __restrict__ bv1,
                                                   unsigned short* __restrict__ Qb,
                                                   unsigned short* __restrict__ Kb,
                                                   unsigned short* __restrict__ Vtb) {
  __shared__ alignas(16) unsigned short As[128 * 64];
  __shared__ alignas(16) unsigned short Bs[128 * 64];
  const int idx = blockIdx.x >> 3;
  const int dir = idx / 3, kind = idx - dir * 3;
  const int n0 = (blockIdx.x & 7) * 128;
  const unsigned short* A =
      (dir == 0) ? (kind == 0 ? tempb : spatb) : (kind == 0 ? spatb : tempb);
  const float* bias = (dir == 0) ? (kind == 0 ? bq0 : (kind == 1 ? bk0 : bv0))
                                 : (kind == 0 ? bq1 : (kind == 1 ? bk1 : bv1));
  const unsigned short* Bt = Wt + ((size_t)(dir * 4 + kind) << 20);

  const int tid = threadIdx.x;
  const int w = tid >> 6, lane = tid & 63;
  const int quad = lane >> 4, l16 = lane & 15;
  const int wm = w & 1, wn = w >> 1;
  const size_t dof = (size_t)dir * NROWS * EMB;

  if (kind == 2) {
    // V: unswapped -> lane holds 4 consecutive keys at fixed d
    f32x4 acc[4][4] = {};
    gemm_core64<0>(A, Bt, blockIdx.y * 128, n0, As, Bs, acc);
    unsigned short* Vt = Vtb + dof;
    const int rowb = blockIdx.y * 128 + wm * 64;
#pragma unroll
    for (int in = 0; in < 4; ++in) {
      const int col = n0 + wn * 64 + in * 16 + l16;
      const int h = col >> 6, d = col & 63;
      const float bvv = bias[col];
#pragma unroll
      for (int im = 0; im < 4; ++im) {
        const int row = rowb + im * 16 + quad * 4;
        const int b = row >> 11, key = row & 2047;
        ushort4 o;
        o.x = f2bf(acc[im][in][0] + bvv);
        o.y = f2bf(acc[im][in][1] + bvv);
        o.z = f2bf(acc[im][in][2] + bvv);
        o.w = f2bf(acc[im][in][3] + bvv);
        *(ushort4*)(Vt + ((size_t)(b * 16 + h) * 64 + d) * SEQ + key) = o;
      }
    }
  } else {
    // Q/K: swapped -> lane reg r = output col nbase+r (contiguous)
    f32x4 acc[4][4] = {};
    gemm_core64<1>(A, Bt, blockIdx.y * 128, n0, As, Bs, acc);
    unsigned short* out = ((kind == 0) ? Qb : Kb) + dof;
    const float scale = (kind == 0) ? 0.18033688011112042f : 1.0f;
    const int rowm = blockIdx.y * 128 + wm * 64;
#pragma unroll
    for (int i = 0; i < 4; ++i) {
      const int ncol = n0 + wn * 64 + i * 16;
      const f32x4 b4 = ((const f32x4*)(bias + ncol))[quad];
      const int nbase = ncol + quad * 4;
#pragma unroll
      for (int j = 0; j < 4; ++j) {
        const int m = rowm + j * 16 + l16;
        ushort4 o;
        o.x = f2bf((acc[i][j][0] + b4[0]) * scale);
        o.y = f2bf((acc[i][j][1] + b4[1]) * scale);
        o.z = f2bf((acc[i][j][2] + b4[2]) * scale);
        o.w = f2bf((acc[i][j][3] + b4[3]) * scale);
        *(ushort4*)(out + (size_t)m * EMB + nbase) = o;
      }
    }
  }
}

// ---------------- output projection GEMM, both dirs: fp32 = acc + bias + resid ----------------
// grid (16, 32): dir = bx>>3, n0 = (bx&7)*128, m0 = by*128. SWAP=1 -> float4 epilogue.
__global__ __launch_bounds__(256, 3) void gemm_o(const unsigned short* __restrict__ Ob,
                                                 const unsigned short* __restrict__ Wt,
                                                 const float* __restrict__ bo0,
                                                 const float* __restrict__ bo1,
                                                 const float* __restrict__ temp,
                                                 const float* __restrict__ spat,
                                                 float* __restrict__ proj) {
  __shared__ alignas(16) unsigned short As[128 * 64];
  __shared__ alignas(16) unsigned short Bs[128 * 64];
  const int dir = blockIdx.x >> 3;
  const int n0 = (blockIdx.x & 7) * 128;
  const size_t dof = (size_t)dir * NROWS * EMB;
  const float* bias = dir ? bo1 : bo0;
  const float* resid = dir ? spat : temp;

  f32x4 acc[4][4] = {};
  gemm_core64<1>(Ob + dof, Wt + ((size_t)(dir * 4 + 3) << 20), blockIdx.y * 128, n0, As, Bs,
                 acc);

  const int tid = threadIdx.x;
  const int w = tid >> 6, lane = tid & 63;
  const int quad = lane >> 4, l16 = lane & 15;
  const int wm = w & 1, wn = w >> 1;
  const int rowm = blockIdx.y * 128 + wm * 64;
  float* outf = proj + dof;
#pragma unroll
  for (int i = 0; i < 4; ++i) {
    const int ncol = n0 + wn * 64 + i * 16;
    const f32x4 b4 = ((const f32x4*)(bias + ncol))[quad];
    const int nbase = ncol + quad * 4;
#pragma unroll
    for (int j = 0; j < 4; ++j) {
      const int m = rowm + j * 16 + l16;
      const size_t off = (size_t)m * EMB + nbase;
      const f32x4 rv = *(const f32x4*)(resid + off);
      f32x4 o = acc[i][j];
      o[0] += b4[0] + rv[0];
      o[1] += b4[1] + rv[1];
      o[2] += b4[2] + rv[2];
      o[3] += b4[3] + rv[3];
      *(f32x4*)(outf + off) = o;
    }
  }
}

// ---------------- flash attention (R4 version): 128 q rows (32/wave), both dirs ----------------
// grid (16, 64): by = dir*32 + bh. Q PRE-SCALED by 0.125*log2(e).
// S^T = K @ Q^T; K/V fragments loaded once, reused for both q-halves.
// Staging via global_load_lds with XOR swizzle folded into the GLOBAL address.
__global__ __launch_bounds__(256, 4) void flash_attn(const unsigned short* __restrict__ Qall,
                                                     const unsigned short* __restrict__ Kall,
                                                     const unsigned short* __restrict__ Vtall,
                                                     unsigned short* __restrict__ Oall) {
  __shared__ alignas(16) unsigned short Ks[64 * 64];  // [key][d], 16B-chunk XOR swizzle
  __shared__ alignas(16) unsigned short Vs[64 * 64];  // [d][key], 16B-chunk XOR swizzle
  __shared__ alignas(16) unsigned short Ps[4][2048];  // per-wave P^T [32 q][64 key]

  const int tid = threadIdx.x;
  const int w = tid >> 6, lane = tid & 63;
  const int quad = lane >> 4, l16 = lane & 15;
  const int dir = blockIdx.y >> 5, bh = blockIdx.y & 31;
  const int b = bh >> 4, h = bh & 15;
  const size_t dof = (size_t)dir * NROWS * EMB;
  const unsigned short* Q = Qall + dof;
  const unsigned short* K = Kall + dof;
  const unsigned short* Vt = Vtall + dof;
  unsigned short* O = Oall + dof;
  const int q0 = blockIdx.x * 128 + w * 32;

  bf16x8 qf[2][2];
#pragma unroll
  for (int qh = 0; qh < 2; ++qh) {
    const unsigned short* Qrow = Q + (size_t)(b * SEQ + q0 + qh * 16 + l16) * EMB + h * 64;
    qf[qh][0] = *(const bf16x8*)(Qrow + quad * 8);
    qf[qh][1] = *(const bf16x8*)(Qrow + 32 + quad * 8);
  }

  bf16x8 onesf;
#pragma unroll
  for (int i = 0; i < 8; ++i) onesf[i] = (__bf16)1.0f;

  f32x4 oaccT[2][4] = {};  // [qh][dg]: O^T[d = dg*16+quad*4+r][q = qh*16+l16]
  f32x4 rs[2] = {};        // rowsum per qh (ones-MFMA, col = q)
  unsigned short* pw = &Ps[w][0];
  const int swz = (l16 & 7) << 1;  // 8B-block XOR swizzle (even)
  const int sw8 = l16 & 7;

  // async staging: wave w owns keys/d-rows [w*16, w*16+16), 2 instrs each (8 rows/instr)
  const int r8 = lane >> 3, p8 = lane & 7;
  const int kr0 = w * 16 + r8, kr1 = kr0 + 8;
  const unsigned short* Ksrc0 = K + (size_t)(b * SEQ + kr0) * EMB + h * 64 + ((p8 ^ (kr0 & 7)) * 8);
  const unsigned short* Ksrc1 = K + (size_t)(b * SEQ + kr1) * EMB + h * 64 + ((p8 ^ (kr1 & 7)) * 8);
  const unsigned short* Vsrc0 = Vt + ((size_t)bh * 64 + kr0) * SEQ + ((p8 ^ (kr0 & 7)) * 8);
  const unsigned short* Vsrc1 = Vt + ((size_t)bh * 64 + kr1) * SEQ + ((p8 ^ (kr1 & 7)) * 8);
  unsigned short* KsW0 = Ks + (w * 16) * 64;
  unsigned short* KsW1 = Ks + (w * 16 + 8) * 64;
  unsigned short* VsW0 = Vs + (w * 16) * 64;
  unsigned short* VsW1 = Vs + (w * 16 + 8) * 64;

  for (int kt = 0; kt < SEQ; kt += 64) {
    __syncthreads();
    async_load16(Ksrc0 + (size_t)kt * EMB, KsW0);
    async_load16(Ksrc1 + (size_t)kt * EMB, KsW1);
    async_load16(Vsrc0 + kt, VsW0);
    async_load16(Vsrc1 + kt, VsW1);
    __syncthreads();

    // S^T = K @ Q^T, then P = exp2(S^T) -> per-wave LDS
#pragma unroll
    for (int g = 0; g < 4; ++g) {
      const int key = g * 16 + l16;
      bf16x8 kf0 = *(const bf16x8*)(Ks + key * 64 + ((quad ^ sw8) * 8));
      bf16x8 kf1 = *(const bf16x8*)(Ks + key * 64 + (((4 + quad) ^ sw8) * 8));
      const int kb = 4 * g + quad;
#pragma unroll
      for (int qh = 0; qh < 2; ++qh) {
        f32x4 z = {};
        z = mfma16(kf0, qf[qh][0], z);
        z = mfma16(kf1, qf[qh][1], z);
        uint2 pk;
        pk.x = (__float_as_uint(__builtin_amdgcn_exp2f(z[0])) >> 16) |
               (__float_as_uint(__builtin_amdgcn_exp2f(z[1])) & 0xffff0000u);
        pk.y = (__float_as_uint(__builtin_amdgcn_exp2f(z[2])) >> 16) |
               (__float_as_uint(__builtin_amdgcn_exp2f(z[3])) & 0xffff0000u);
        *(uint2*)(pw + (qh * 16 + l16) * 64 + ((kb ^ swz) << 2)) = pk;
      }
    }
    asm volatile("" ::: "memory");
    bf16x8 pb[2][2];
#pragma unroll
    for (int qh = 0; qh < 2; ++qh) {
      const int qrow = qh * 16 + l16;
      pb[qh][0] = *(const bf16x8*)(pw + qrow * 64 + (((2 * quad) ^ swz) << 2));
      pb[qh][1] = *(const bf16x8*)(pw + qrow * 64 + (((8 + 2 * quad) ^ swz) << 2));
      rs[qh] = mfma16(onesf, pb[qh][1], mfma16(onesf, pb[qh][0], rs[qh]));
    }
    asm volatile("" ::: "memory");
    // O^T += V^T @ P^T (V fragments shared across q-halves)
#pragma unroll
    for (int dg = 0; dg < 4; ++dg) {
      const int dd = dg * 16 + l16;
      bf16x8 v0 = *(const bf16x8*)(Vs + dd * 64 + ((quad ^ sw8) * 8));
      bf16x8 v1 = *(const bf16x8*)(Vs + dd * 64 + (((4 + quad) ^ sw8) * 8));
#pragma unroll
      for (int qh = 0; qh < 2; ++qh) {
        oaccT[qh][dg] = mfma16(v0, pb[qh][0], oaccT[qh][dg]);
        oaccT[qh][dg] = mfma16(v1, pb[qh][1], oaccT[qh][dg]);
      }
    }
    asm volatile("" ::: "memory");
  }

  // epilogue: per q-half, transpose O^T back through per-wave Ps, store coalesced
#pragma unroll
  for (int qh = 0; qh < 2; ++qh) {
    const float inv = 1.0f / rs[qh][0];
#pragma unroll
    for (int dg = 0; dg < 4; ++dg) {
      uint2 pk;
      pk.x = (unsigned int)f2bf(oaccT[qh][dg][0] * inv) |
             ((unsigned int)f2bf(oaccT[qh][dg][1] * inv) << 16);
      pk.y = (unsigned int)f2bf(oaccT[qh][dg][2] * inv) |
             ((unsigned int)f2bf(oaccT[qh][dg][3] * inv) << 16);
      const int kb = 4 * dg + quad;
      *(uint2*)(pw + l16 * 64 + ((kb ^ swz) << 2)) = pk;
    }
    asm volatile("" ::: "memory");
    const int qq = lane >> 2, cc = lane & 3;
    const int swq = (qq & 7) << 1;
    ushort8 r0 = *(const ushort8*)(pw + qq * 64 + (((4 * cc) ^ swq) << 2));
    ushort8 r1 = *(const ushort8*)(pw + qq * 64 + (((4 * cc + 2) ^ swq) << 2));
    unsigned short* Orow = O + (size_t)(b * SEQ + q0 + qh * 16 + qq) * EMB + h * 64 + cc * 16;
    *(ushort8*)(Orow) = r0;
    *(ushort8*)(Orow + 8) = r1;
    asm volatile("" ::: "memory");
  }
}

// ---------------- layernorm: one block per row, both dirs ----------------
__global__ __launch_bounds__(256) void ln_k(const float* __restrict__ X,
                                            const float* __restrict__ g,
                                            const float* __restrict__ bb,
                                            float* __restrict__ out) {
  const int row = blockIdx.x;
  const int tid = threadIdx.x;
  const float4 v = ((const float4*)(X + (size_t)row * EMB))[tid];
  float s = v.x + v.y + v.z + v.w;
  float s2 = v.x * v.x + v.y * v.y + v.z * v.z + v.w * v.w;
#pragma unroll
  for (int o = 32; o > 0; o >>= 1) {
    s += __shfl_down(s, o);
    s2 += __shfl_down(s2, o);
  }
  __shared__ float ws[4], ws2[4];
  if ((tid & 63) == 0) { ws[tid >> 6] = s; ws2[tid >> 6] = s2; }
  __syncthreads();
  const float S = ws[0] + ws[1] + ws[2] + ws[3];
  const float S2 = ws2[0] + ws2[1] + ws2[2] + ws2[3];
  const float mu = S * (1.f / EMB);
  const float inv = rsqrtf(S2 * (1.f / EMB) - mu * mu + 1e-5f);
  const float4 gv = ((const float4*)g)[tid];
  const float4 bv = ((const float4*)bb)[tid];
  float4 o4;
  o4.x = (v.x - mu) * inv * gv.x + bv.x;
  o4.y = (v.y - mu) * inv * gv.y + bv.y;
  o4.z = (v.z - mu) * inv * gv.z + bv.z;
  o4.w = (v.w - mu) * inv * gv.w + bv.w;
  ((float4*)(out + (size_t)row * EMB))[tid] = o4;
}

extern "C" void kernel_launch(void* const* d_in, const int* in_sizes, int n_in,
                              void* d_out, int out_size, void* d_ws, size_t ws_size,
                              hipStream_t stream) {
  const float* temp = (const float*)d_in[0];
  const float* spat = (const float*)d_in[1];
  // t2s weights: d_in[2..9], s2t weights: d_in[10..17]
  const float* lng = (const float*)d_in[18];
  const float* lnb = (const float*)d_in[19];
  float* out = (float*)d_out;

  char* base = (char*)d_ws;
  unsigned short* tempb = (unsigned short*)(base + ((size_t)0 << 20));
  unsigned short* spatb = (unsigned short*)(base + ((size_t)8 << 20));
  unsigned short* Wt = (unsigned short*)(base + ((size_t)16 << 20));   // 8 x 1024x1024 bf16
  unsigned short* Qb = (unsigned short*)(base + ((size_t)32 << 20));   // 2 dirs
  unsigned short* Kb = (unsigned short*)(base + ((size_t)48 << 20));
  unsigned short* Vtb = (unsigned short*)(base + ((size_t)64 << 20));
  unsigned short* Ob = (unsigned short*)(base + ((size_t)80 << 20));
  float* proj = (float*)(base + ((size_t)32 << 20));  // aliases Qb+Kb (dead after flash)

  cvt2<<<8192, 256, 0, stream>>>(temp, spat, tempb, spatb);
  // Wt order: dir0 = s2t {Wq,Wk,Wv,Wo} = d_in[10,12,14,16]; dir1 = t2s = d_in[2,4,6,8]
  wtrans8<<<dim3(16, 16, 8), 256, 0, stream>>>(
      (const float*)d_in[10], (const float*)d_in[12], (const float*)d_in[14],
      (const float*)d_in[16], (const float*)d_in[2], (const float*)d_in[4],
      (const float*)d_in[6], (const float*)d_in[8], Wt);
  gemm_qkv<<<dim3(48, 32), 256, 0, stream>>>(
      tempb, spatb, Wt, (const float*)d_in[11], (const float*)d_in[13],
      (const float*)d_in[15], (const float*)d_in[3], (const float*)d_in[5],
      (const float*)d_in[7], Qb, Kb, Vtb);
  flash_attn<<<dim3(16, 64), 256, 0, stream>>>(Qb, Kb, Vtb, Ob);
  gemm_o<<<dim3(16, 32), 256, 0, stream>>>(Ob, Wt, (const float*)d_in[17],
                                           (const float*)d_in[9], temp, spat, proj);
  ln_k<<<2 * NROWS, 256, 0, stream>>>(proj, lng, lnb, out);
}

// Round 9
// 325.653 us; speedup vs baseline: 1.0409x; 1.0409x over previous
//
#include <hip/hip_runtime.h>
#include <stdint.h>

#define SEQ 2048
#define EMB 1024
#define NROWS 4096  // 2 batches * 2048

typedef __bf16 bf16x8 __attribute__((ext_vector_type(8)));
typedef float f32x4 __attribute__((ext_vector_type(4)));
typedef unsigned short ushort8 __attribute__((ext_vector_type(8)));

__device__ __forceinline__ unsigned short f2bf(float f) {
  unsigned int u = __float_as_uint(f);
  u += 0x7fffu + ((u >> 16) & 1u);
  return (unsigned short)(u >> 16);
}

__device__ __forceinline__ float bf2f(unsigned short h) {
  return __uint_as_float((unsigned int)h << 16);
}

__device__ __forceinline__ f32x4 mfma16(bf16x8 a, bf16x8 b, f32x4 c) {
  return __builtin_amdgcn_mfma_f32_16x16x32_bf16(a, b, c, 0, 0, 0);
}

// async global->LDS, 16B per lane; lds dest = wave-uniform base + lane*16
__device__ __forceinline__ void async_load16(const void* g, void* l) {
  auto gp = reinterpret_cast<__attribute__((address_space(1))) void*>(
      reinterpret_cast<uintptr_t>(g));
  auto lp = reinterpret_cast<__attribute__((address_space(3))) void*>(
      reinterpret_cast<uintptr_t>(l));
  __builtin_amdgcn_global_load_lds(gp, lp, 16, 0, 0);
}

// ------- prep: fp32->bf16 convert of both inputs + 8x weight transpose, ONE launch -------
// blocks [0, 8192): cvt (4 float4 per thread-block row); blocks [8192, 10240): wtrans.
__global__ __launch_bounds__(256) void prep(const float* __restrict__ t,
                                            const float* __restrict__ s,
                                            unsigned short* __restrict__ tb,
                                            unsigned short* __restrict__ sb,
                                            const float* __restrict__ W0,
                                            const float* __restrict__ W1,
                                            const float* __restrict__ W2,
                                            const float* __restrict__ W3,
                                            const float* __restrict__ W4,
                                            const float* __restrict__ W5,
                                            const float* __restrict__ W6,
                                            const float* __restrict__ W7,
                                            unsigned short* __restrict__ Wt) {
  const int bx = blockIdx.x;
  if (bx < 8192) {
    int i = bx * 256 + threadIdx.x;
    const float* x; unsigned short* y;
    if (i < NROWS * EMB / 4) { x = t; y = tb; }
    else { x = s; y = sb; i -= NROWS * EMB / 4; }
    float4 v = ((const float4*)x)[i];
    ushort4 o;
    o.x = f2bf(v.x); o.y = f2bf(v.y); o.z = f2bf(v.z); o.w = f2bf(v.w);
    ((ushort4*)y)[i] = o;
    return;
  }
  const int e = bx - 8192;
  const int z = e >> 8, tt = e & 255;
  const float* Ws[8] = {W0, W1, W2, W3, W4, W5, W6, W7};
  const float* W = Ws[z];
  unsigned short* dst = Wt + ((size_t)z << 20);
  __shared__ unsigned short tile[64][65];
  const int n0 = (tt & 15) * 64, k0 = (tt >> 4) * 64;
#pragma unroll
  for (int i = 0; i < 16; ++i) {
    const int ee = i * 256 + threadIdx.x;
    const int kk = ee >> 6, nn = ee & 63;
    tile[kk][nn] = f2bf(W[(size_t)(k0 + kk) * EMB + n0 + nn]);
  }
  __syncthreads();
#pragma unroll
  for (int i = 0; i < 16; ++i) {
    const int ee = i * 256 + threadIdx.x;
    const int nn = ee >> 6, kk = ee & 63;
    dst[(size_t)(n0 + nn) * EMB + k0 + kk] = tile[kk][nn];
  }
}

// ------- 128x128 GEMM core, BK=64, XOR-swizzled LDS (conflict-free), 32 MFMA/iter -------
// Swizzle folded into GLOBAL source address (LDS dest stays linear for global_load_lds).
__device__ __forceinline__ void gemm_core64(const unsigned short* __restrict__ A,
                                            const unsigned short* __restrict__ Bt,
                                            int m0, int bt0,
                                            unsigned short* As, unsigned short* Bs,
                                            f32x4 (&acc)[4][4]) {
  const int tid = threadIdx.x;
  const int w = tid >> 6, lane = tid & 63;
  const int quad = lane >> 4, l16 = lane & 15;
  const int wm = w & 1, wn = w >> 1;
  const int sw8 = l16 & 7;

  // staging: wave w owns rows [w*32, w*32+32) of both As and Bs; 4 instrs each
  const int srow = lane >> 3, p8 = lane & 7;
  const unsigned short* Ag[4];
  const unsigned short* Bg[4];
#pragma unroll
  for (int i = 0; i < 4; ++i) {
    const int r = w * 32 + i * 8 + srow;
    Ag[i] = A + (size_t)(m0 + r) * EMB + ((p8 ^ (r & 7)) * 8);
    Bg[i] = Bt + (size_t)(bt0 + r) * EMB + ((p8 ^ (r & 7)) * 8);
  }
  unsigned short* AsB[4];
  unsigned short* BsB[4];
#pragma unroll
  for (int i = 0; i < 4; ++i) {
    AsB[i] = As + (w * 32 + i * 8) * 64;
    BsB[i] = Bs + (w * 32 + i * 8) * 64;
  }

  for (int kk = 0; kk < EMB; kk += 64) {
    __syncthreads();
#pragma unroll
    for (int i = 0; i < 4; ++i) {
      async_load16(Ag[i] + kk, AsB[i]);
      async_load16(Bg[i] + kk, BsB[i]);
    }
    __syncthreads();
#pragma unroll
    for (int h = 0; h < 2; ++h) {
      bf16x8 af[4], bfr[4];
#pragma unroll
      for (int im = 0; im < 4; ++im)
        af[im] = *(const bf16x8*)(As + (wm * 64 + im * 16 + l16) * 64 +
                                  (((h * 4 + quad) ^ sw8) * 8));
#pragma unroll
      for (int in = 0; in < 4; ++in)
        bfr[in] = *(const bf16x8*)(Bs + (wn * 64 + in * 16 + l16) * 64 +
                                   (((h * 4 + quad) ^ sw8) * 8));
#pragma unroll
      for (int im = 0; im < 4; ++im)
#pragma unroll
        for (int in = 0; in < 4; ++in)
          acc[im][in] = mfma16(af[im], bfr[in], acc[im][in]);
    }
  }
}

// ---------------- fused Q|K|V projection GEMM, BOTH directions ----------------
// grid (48, 32): idx = bx>>3 in 0..5 = dir*3 + {Q,K,V}; n0 = (bx&7)*128; m0 = by*128.
// dir0 = s2t (q from temp, kv from spat), dir1 = t2s.
// Q pre-scaled by 0.125*log2(e). V written TRANSPOSED into Vt[bh][d][key].
__global__ __launch_bounds__(256, 3) void gemm_qkv(const unsigned short* __restrict__ tempb,
                                                   const unsigned short* __restrict__ spatb,
                                                   const unsigned short* __restrict__ Wt,
                                                   const float* __restrict__ bq0,
                                                   const float* __restrict__ bk0,
                                                   const float* __restrict__ bv0,
                                                   const float* __restrict__ bq1,
                                                   const float* __restrict__ bk1,
                                                   const float* __restrict__ bv1,
                                                   unsigned short* __restrict__ Qb,
                                                   unsigned short* __restrict__ Kb,
                                                   unsigned short* __restrict__ Vtb) {
  __shared__ alignas(16) unsigned short As[128 * 64];
  __shared__ alignas(16) unsigned short Bs[128 * 64];
  const int idx = blockIdx.x >> 3;
  const int dir = idx / 3, kind = idx - dir * 3;
  const int n0 = (blockIdx.x & 7) * 128;
  const unsigned short* A =
      (dir == 0) ? (kind == 0 ? tempb : spatb) : (kind == 0 ? spatb : tempb);
  const float* bias = (dir == 0) ? (kind == 0 ? bq0 : (kind == 1 ? bk0 : bv0))
                                 : (kind == 0 ? bq1 : (kind == 1 ? bk1 : bv1));

  f32x4 acc[4][4] = {};
  gemm_core64(A, Wt + ((size_t)(dir * 4 + kind) << 20), blockIdx.y * 128, n0, As, Bs, acc);

  const int tid = threadIdx.x;
  const int w = tid >> 6, lane = tid & 63;
  const int quad = lane >> 4, l16 = lane & 15;
  const int wm = w & 1, wn = w >> 1;
  const int rowb = blockIdx.y * 128 + wm * 64;
  const size_t dof = (size_t)dir * NROWS * EMB;

  if (kind == 2) {
    // V: write transposed into Vt[dir][(b*16+h)*64 + d][key]
    unsigned short* Vt = Vtb + dof;
#pragma unroll
    for (int in = 0; in < 4; ++in) {
      const int col = n0 + wn * 64 + in * 16 + l16;
      const int h = col >> 6, d = col & 63;
      const float bvv = bias[col];
#pragma unroll
      for (int im = 0; im < 4; ++im) {
        const int row = rowb + im * 16 + quad * 4;
        const int b = row >> 11, key = row & 2047;
        ushort4 o;
        o.x = f2bf(acc[im][in][0] + bvv);
        o.y = f2bf(acc[im][in][1] + bvv);
        o.z = f2bf(acc[im][in][2] + bvv);
        o.w = f2bf(acc[im][in][3] + bvv);
        *(ushort4*)(Vt + ((size_t)(b * 16 + h) * 64 + d) * SEQ + key) = o;
      }
    }
  } else {
    unsigned short* out = ((kind == 0) ? Qb : Kb) + dof;
    const float scale = (kind == 0) ? 0.18033688011112042f : 1.0f;
#pragma unroll
    for (int in = 0; in < 4; ++in) {
      const int col = n0 + wn * 64 + in * 16 + l16;
      const float bvv = bias[col];
#pragma unroll
      for (int im = 0; im < 4; ++im)
#pragma unroll
        for (int r = 0; r < 4; ++r) {
          const int row = rowb + im * 16 + quad * 4 + r;
          out[(size_t)row * EMB + col] = f2bf((acc[im][in][r] + bvv) * scale);
        }
    }
  }
}

// ------- output projection GEMM, both dirs: projb (bf16) = acc + bias + resid -------
// grid (16, 32): dir = bx>>3, n0 = (bx&7)*128, m0 = by*128.
__global__ __launch_bounds__(256, 3) void gemm_o(const unsigned short* __restrict__ Ob,
                                                 const unsigned short* __restrict__ Wt,
                                                 const float* __restrict__ bo0,
                                                 const float* __restrict__ bo1,
                                                 const float* __restrict__ temp,
                                                 const float* __restrict__ spat,
                                                 unsigned short* __restrict__ projb) {
  __shared__ alignas(16) unsigned short As[128 * 64];
  __shared__ alignas(16) unsigned short Bs[128 * 64];
  const int dir = blockIdx.x >> 3;
  const int n0 = (blockIdx.x & 7) * 128;
  const size_t dof = (size_t)dir * NROWS * EMB;
  const float* bias = dir ? bo1 : bo0;
  const float* resid = dir ? spat : temp;

  f32x4 acc[4][4] = {};
  gemm_core64(Ob + dof, Wt + ((size_t)(dir * 4 + 3) << 20), blockIdx.y * 128, n0, As, Bs,
              acc);

  const int tid = threadIdx.x;
  const int w = tid >> 6, lane = tid & 63;
  const int quad = lane >> 4, l16 = lane & 15;
  const int wm = w & 1, wn = w >> 1;
  const int rowb = blockIdx.y * 128 + wm * 64;
  unsigned short* outb = projb + dof;
#pragma unroll
  for (int in = 0; in < 4; ++in) {
    const int col = n0 + wn * 64 + in * 16 + l16;
    const float bvv = bias[col];
#pragma unroll
    for (int im = 0; im < 4; ++im)
#pragma unroll
      for (int r = 0; r < 4; ++r) {
        const int row = rowb + im * 16 + quad * 4 + r;
        const size_t off = (size_t)row * EMB + col;
        outb[off] = f2bf(acc[im][in][r] + bvv + resid[off]);
      }
  }
}

// ---------------- flash attention (R4 version): 128 q rows (32/wave), both dirs ----------------
// grid (16, 64): by = dir*32 + bh. Q PRE-SCALED by 0.125*log2(e).
// S^T = K @ Q^T; K/V fragments loaded once, reused for both q-halves.
// Staging via global_load_lds with XOR swizzle folded into the GLOBAL address.
__global__ __launch_bounds__(256, 4) void flash_attn(const unsigned short* __restrict__ Qall,
                                                     const unsigned short* __restrict__ Kall,
                                                     const unsigned short* __restrict__ Vtall,
                                                     unsigned short* __restrict__ Oall) {
  __shared__ alignas(16) unsigned short Ks[64 * 64];  // [key][d], 16B-chunk XOR swizzle
  __shared__ alignas(16) unsigned short Vs[64 * 64];  // [d][key], 16B-chunk XOR swizzle
  __shared__ alignas(16) unsigned short Ps[4][2048];  // per-wave P^T [32 q][64 key]

  const int tid = threadIdx.x;
  const int w = tid >> 6, lane = tid & 63;
  const int quad = lane >> 4, l16 = lane & 15;
  const int dir = blockIdx.y >> 5, bh = blockIdx.y & 31;
  const int b = bh >> 4, h = bh & 15;
  const size_t dof = (size_t)dir * NROWS * EMB;
  const unsigned short* Q = Qall + dof;
  const unsigned short* K = Kall + dof;
  const unsigned short* Vt = Vtall + dof;
  unsigned short* O = Oall + dof;
  const int q0 = blockIdx.x * 128 + w * 32;

  bf16x8 qf[2][2];
#pragma unroll
  for (int qh = 0; qh < 2; ++qh) {
    const unsigned short* Qrow = Q + (size_t)(b * SEQ + q0 + qh * 16 + l16) * EMB + h * 64;
    qf[qh][0] = *(const bf16x8*)(Qrow + quad * 8);
    qf[qh][1] = *(const bf16x8*)(Qrow + 32 + quad * 8);
  }

  bf16x8 onesf;
#pragma unroll
  for (int i = 0; i < 8; ++i) onesf[i] = (__bf16)1.0f;

  f32x4 oaccT[2][4] = {};  // [qh][dg]: O^T[d = dg*16+quad*4+r][q = qh*16+l16]
  f32x4 rs[2] = {};        // rowsum per qh (ones-MFMA, col = q)
  unsigned short* pw = &Ps[w][0];
  const int swz = (l16 & 7) << 1;  // 8B-block XOR swizzle (even)
  const int sw8 = l16 & 7;

  // async staging: wave w owns keys/d-rows [w*16, w*16+16), 2 instrs each (8 rows/instr)
  const int r8 = lane >> 3, p8 = lane & 7;
  const int kr0 = w * 16 + r8, kr1 = kr0 + 8;
  const unsigned short* Ksrc0 = K + (size_t)(b * SEQ + kr0) * EMB + h * 64 + ((p8 ^ (kr0 & 7)) * 8);
  const unsigned short* Ksrc1 = K + (size_t)(b * SEQ + kr1) * EMB + h * 64 + ((p8 ^ (kr1 & 7)) * 8);
  const unsigned short* Vsrc0 = Vt + ((size_t)bh * 64 + kr0) * SEQ + ((p8 ^ (kr0 & 7)) * 8);
  const unsigned short* Vsrc1 = Vt + ((size_t)bh * 64 + kr1) * SEQ + ((p8 ^ (kr1 & 7)) * 8);
  unsigned short* KsW0 = Ks + (w * 16) * 64;
  unsigned short* KsW1 = Ks + (w * 16 + 8) * 64;
  unsigned short* VsW0 = Vs + (w * 16) * 64;
  unsigned short* VsW1 = Vs + (w * 16 + 8) * 64;

  for (int kt = 0; kt < SEQ; kt += 64) {
    __syncthreads();
    async_load16(Ksrc0 + (size_t)kt * EMB, KsW0);
    async_load16(Ksrc1 + (size_t)kt * EMB, KsW1);
    async_load16(Vsrc0 + kt, VsW0);
    async_load16(Vsrc1 + kt, VsW1);
    __syncthreads();

    // S^T = K @ Q^T, then P = exp2(S^T) -> per-wave LDS
#pragma unroll
    for (int g = 0; g < 4; ++g) {
      const int key = g * 16 + l16;
      bf16x8 kf0 = *(const bf16x8*)(Ks + key * 64 + ((quad ^ sw8) * 8));
      bf16x8 kf1 = *(const bf16x8*)(Ks + key * 64 + (((4 + quad) ^ sw8) * 8));
      const int kb = 4 * g + quad;
#pragma unroll
      for (int qh = 0; qh < 2; ++qh) {
        f32x4 z = {};
        z = mfma16(kf0, qf[qh][0], z);
        z = mfma16(kf1, qf[qh][1], z);
        uint2 pk;
        pk.x = (__float_as_uint(__builtin_amdgcn_exp2f(z[0])) >> 16) |
               (__float_as_uint(__builtin_amdgcn_exp2f(z[1])) & 0xffff0000u);
        pk.y = (__float_as_uint(__builtin_amdgcn_exp2f(z[2])) >> 16) |
               (__float_as_uint(__builtin_amdgcn_exp2f(z[3])) & 0xffff0000u);
        *(uint2*)(pw + (qh * 16 + l16) * 64 + ((kb ^ swz) << 2)) = pk;
      }
    }
    asm volatile("" ::: "memory");
    bf16x8 pb[2][2];
#pragma unroll
    for (int qh = 0; qh < 2; ++qh) {
      const int qrow = qh * 16 + l16;
      pb[qh][0] = *(const bf16x8*)(pw + qrow * 64 + (((2 * quad) ^ swz) << 2));
      pb[qh][1] = *(const bf16x8*)(pw + qrow * 64 + (((8 + 2 * quad) ^ swz) << 2));
      rs[qh] = mfma16(onesf, pb[qh][1], mfma16(onesf, pb[qh][0], rs[qh]));
    }
    asm volatile("" ::: "memory");
    // O^T += V^T @ P^T (V fragments shared across q-halves)
#pragma unroll
    for (int dg = 0; dg < 4; ++dg) {
      const int dd = dg * 16 + l16;
      bf16x8 v0 = *(const bf16x8*)(Vs + dd * 64 + ((quad ^ sw8) * 8));
      bf16x8 v1 = *(const bf16x8*)(Vs + dd * 64 + (((4 + quad) ^ sw8) * 8));
#pragma unroll
      for (int qh = 0; qh < 2; ++qh) {
        oaccT[qh][dg] = mfma16(v0, pb[qh][0], oaccT[qh][dg]);
        oaccT[qh][dg] = mfma16(v1, pb[qh][1], oaccT[qh][dg]);
      }
    }
    asm volatile("" ::: "memory");
  }

  // epilogue: per q-half, transpose O^T back through per-wave Ps, store coalesced
#pragma unroll
  for (int qh = 0; qh < 2; ++qh) {
    const float inv = 1.0f / rs[qh][0];
#pragma unroll
    for (int dg = 0; dg < 4; ++dg) {
      uint2 pk;
      pk.x = (unsigned int)f2bf(oaccT[qh][dg][0] * inv) |
             ((unsigned int)f2bf(oaccT[qh][dg][1] * inv) << 16);
      pk.y = (unsigned int)f2bf(oaccT[qh][dg][2] * inv) |
             ((unsigned int)f2bf(oaccT[qh][dg][3] * inv) << 16);
      const int kb = 4 * dg + quad;
      *(uint2*)(pw + l16 * 64 + ((kb ^ swz) << 2)) = pk;
    }
    asm volatile("" ::: "memory");
    const int qq = lane >> 2, cc = lane & 3;
    const int swq = (qq & 7) << 1;
    ushort8 r0 = *(const ushort8*)(pw + qq * 64 + (((4 * cc) ^ swq) << 2));
    ushort8 r1 = *(const ushort8*)(pw + qq * 64 + (((4 * cc + 2) ^ swq) << 2));
    unsigned short* Orow = O + (size_t)(b * SEQ + q0 + qh * 16 + qq) * EMB + h * 64 + cc * 16;
    *(ushort8*)(Orow) = r0;
    *(ushort8*)(Orow + 8) = r1;
    asm volatile("" ::: "memory");
  }
}

// ---------------- layernorm: one block per row, both dirs; bf16 input, fp32 math ----------------
__global__ __launch_bounds__(256) void ln_k(const unsigned short* __restrict__ X,
                                            const float* __restrict__ g,
                                            const float* __restrict__ bb,
                                            float* __restrict__ out) {
  const int row = blockIdx.x;
  const int tid = threadIdx.x;
  const ushort4 hv = ((const ushort4*)(X + (size_t)row * EMB))[tid];
  float4 v;
  v.x = bf2f(hv.x); v.y = bf2f(hv.y); v.z = bf2f(hv.z); v.w = bf2f(hv.w);
  float s = v.x + v.y + v.z + v.w;
  float s2 = v.x * v.x + v.y * v.y + v.z * v.z + v.w * v.w;
#pragma unroll
  for (int o = 32; o > 0; o >>= 1) {
    s += __shfl_down(s, o);
    s2 += __shfl_down(s2, o);
  }
  __shared__ float ws[4], ws2[4];
  if ((tid & 63) == 0) { ws[tid >> 6] = s; ws2[tid >> 6] = s2; }
  __syncthreads();
  const float S = ws[0] + ws[1] + ws[2] + ws[3];
  const float S2 = ws2[0] + ws2[1] + ws2[2] + ws2[3];
  const float mu = S * (1.f / EMB);
  const float inv = rsqrtf(S2 * (1.f / EMB) - mu * mu + 1e-5f);
  const float4 gv = ((const float4*)g)[tid];
  const float4 bv = ((const float4*)bb)[tid];
  float4 o4;
  o4.x = (v.x - mu) * inv * gv.x + bv.x;
  o4.y = (v.y - mu) * inv * gv.y + bv.y;
  o4.z = (v.z - mu) * inv * gv.z + bv.z;
  o4.w = (v.w - mu) * inv * gv.w + bv.w;
  ((float4*)(out + (size_t)row * EMB))[tid] = o4;
}

extern "C" void kernel_launch(void* const* d_in, const int* in_sizes, int n_in,
                              void* d_out, int out_size, void* d_ws, size_t ws_size,
                              hipStream_t stream) {
  const float* temp = (const float*)d_in[0];
  const float* spat = (const float*)d_in[1];
  // t2s weights: d_in[2..9], s2t weights: d_in[10..17]
  const float* lng = (const float*)d_in[18];
  const float* lnb = (const float*)d_in[19];
  float* out = (float*)d_out;

  char* base = (char*)d_ws;
  unsigned short* tempb = (unsigned short*)(base + ((size_t)0 << 20));
  unsigned short* spatb = (unsigned short*)(base + ((size_t)8 << 20));
  unsigned short* Wt = (unsigned short*)(base + ((size_t)16 << 20));   // 8 x 1024x1024 bf16
  unsigned short* Qb = (unsigned short*)(base + ((size_t)32 << 20));   // 2 dirs
  unsigned short* Kb = (unsigned short*)(base + ((size_t)48 << 20));
  unsigned short* Vtb = (unsigned short*)(base + ((size_t)64 << 20));
  unsigned short* Ob = (unsigned short*)(base + ((size_t)80 << 20));
  unsigned short* projb = (unsigned short*)(base + ((size_t)32 << 20));  // aliases Qb (dead after flash)

  // Wt order: dir0 = s2t {Wq,Wk,Wv,Wo} = d_in[10,12,14,16]; dir1 = t2s = d_in[2,4,6,8]
  prep<<<8192 + 2048, 256, 0, stream>>>(
      temp, spat, tempb, spatb, (const float*)d_in[10], (const float*)d_in[12],
      (const float*)d_in[14], (const float*)d_in[16], (const float*)d_in[2],
      (const float*)d_in[4], (const float*)d_in[6], (const float*)d_in[8], Wt);
  gemm_qkv<<<dim3(48, 32), 256, 0, stream>>>(
      tempb, spatb, Wt, (const float*)d_in[11], (const float*)d_in[13],
      (const float*)d_in[15], (const float*)d_in[3], (const float*)d_in[5],
      (const float*)d_in[7], Qb, Kb, Vtb);
  flash_attn<<<dim3(16, 64), 256, 0, stream>>>(Qb, Kb, Vtb, Ob);
  gemm_o<<<dim3(16, 32), 256, 0, stream>>>(Ob, Wt, (const float*)d_in[17],
                                           (const float*)d_in[9], temp, spat, projb);
  ln_k<<<2 * NROWS, 256, 0, stream>>>(projb, lng, lnb, out);
}